// Round 9
// baseline (102.453 us; speedup 1.0000x reference)
//
#include <hip/hip_runtime.h>

// HTMM: B_TREES=8, ARITY=4, DEPTH=8, C=8, M=100, NGEN=4
constexpr int OFFS1 = 8, OFFS2 = 40, OFFS3 = 168, OFFS4 = 680;
constexpr int OFFS5 = 2728, OFFS6 = 10920, OFFS7 = 43688, OFFS8 = 174760;

// lane mapping within a 32-lane group: r = g*8+s (g = gen, s = state), h = s>>2
// wtd_l[(j*8+d)*32 + g*8+s] = P(child=s | parent=d, pos j, gen g)
// wtdT[(j*32+s*4+g)*10 + d] = transposed over parent d (stride 10, 8B-aligned)
// wupT[(j*32+s*4+g)*10 + c] = P(child=c | parent=s, j, g), natural over c
// emt_l[m*36 + g*8+c] = P(obs m | state c, gen g) — ROW STRIDE 36 so row base
//   bank = 4m mod 32 (8 spread starts); stride 32 put every row at bank 0 ->
//   ~8-way conflicts on the E-dot b128 reads (r8: 1.1M SQ_LDS_BANK_CONFLICT).
// pit_l[g*8+c] = root prior
//
// r9 structure (r8 post-mortem): rolled q6 loop for I-cache residency, but q7
// FULLY UNROLLED with STATIC register weights (wtd_p/wup_p) so the hot body
// has zero LDS weight reads and r6's instruction count at r8's issue
// efficiency. Runtime-q6 ops (u6 dot, rat6 fold = 8/subtree) use LDS wtdT/wupT.

template <int CTRL>
static __device__ __forceinline__ float dppmov(float v) {
  return __int_as_float(__builtin_amdgcn_update_dpp(0, __float_as_int(v), CTRL, 0xF, 0xF, true));
}

// octet all-reduce sum, result broadcast to all 8 lanes. Pure DPP (no LDS).
static __device__ __forceinline__ float bfly8(float v) {
  v += dppmov<0xB1>(v);   // quad_perm [1,0,3,2]  (xor 1)
  v += dppmov<0x4E>(v);   // quad_perm [2,3,0,1]  (xor 2)
  v += dppmov<0x141>(v);  // row_half_mirror      (cross-quad within octet)
  return v;
}

// gather own-octet values: pv[k] = v[oct | 4h+k], pv[4+k] = v[oct | 7-4h-k]
static __device__ __forceinline__ void oct8(float v, float pv[8]) {
  float m = dppmov<0x141>(v);  // half-mirror: m[l] = v[oct | 7-(l&7)]
  pv[0] = dppmov<0x00>(v); pv[1] = dppmov<0x55>(v);
  pv[2] = dppmov<0xAA>(v); pv[3] = dppmov<0xFF>(v);
  pv[4] = dppmov<0x00>(m); pv[5] = dppmov<0x55>(m);
  pv[6] = dppmov<0xAA>(m); pv[7] = dppmov<0xFF>(m);
}

static __device__ __forceinline__ float dot8(const float w[8], const float v[8]) {
  return w[0]*v[0] + w[1]*v[1] + w[2]*v[2] + w[3]*v[3] +
         w[4]*v[4] + w[5]*v[5] + w[6]*v[6] + w[7]*v[7];
}

// load 8 consecutive floats permuted to the oct8 register order
static __device__ __forceinline__ void ld8p(const float* p, float wp[8], int h) {
  const float4* q = (const float4*)p;
  float4 a = q[h], b = q[1 - h];
  wp[0] = a.x; wp[1] = a.y; wp[2] = a.z; wp[3] = a.w;
  wp[4] = b.w; wp[5] = b.z; wp[6] = b.y; wp[7] = b.x;
}

// dot of a permuted register 8-vector with a natural-order 8-vector in LDS (2x b128)
static __device__ __forceinline__ float dot8p(const float wp[8], const float* p, int h) {
  const float4* q = (const float4*)p;
  float4 a = q[h], b = q[1 - h];
  return wp[0]*a.x + wp[1]*a.y + wp[2]*a.z + wp[3]*a.w +
         wp[4]*b.w + wp[5]*b.z + wp[6]*b.y + wp[7]*b.x;
}

// same dot but via 4x b64 from a stride-10 table row
static __device__ __forceinline__ float dot8pT(const float wp[8], const float* row, int h) {
  const float2* q = (const float2*)row;
  float2 a = q[2 * h], b = q[2 * h + 1], c = q[3 - 2 * h], d = q[2 - 2 * h];
  return wp[0]*a.x + wp[1]*a.y + wp[2]*b.x + wp[3]*b.y +
         wp[4]*c.y + wp[5]*c.x + wp[6]*d.y + wp[7]*d.x;
}

static __device__ __forceinline__ float rcpf(float x) { return __builtin_amdgcn_rcpf(x); }

// top-down step via wtdT: v_new[s] = sum_d P(s|d,j,g) v[d]   (runtime j ok)
static __device__ __forceinline__ float step_downT(const float* wtdT, float v, int j,
                                                   int sg, int h) {
  float pv[8];
  oct8(v, pv);
  return dot8pT(pv, &wtdT[(j * 32 + sg) * 10], h);
}

// top-down step via wtd_l scalar gather (k_phase2 tail; cold path)
static __device__ __forceinline__ float step_down(const float* wtd_l, float v, int j,
                                                  int r, int h) {
  const float* wb = &wtd_l[j * 256 + r];
  float w[8];
#pragma unroll
  for (int k = 0; k < 4; k++) {
    w[k]     = wb[(4 * h + k) * 32];
    w[4 + k] = wb[(7 - 4 * h - k) * 32];
  }
  float pv[8];
  oct8(v, pv);
  return dot8(w, pv);
}

// upward product over 4 children with register weight rows (static j)
static __device__ __forceinline__ float upprod(const float wup_p[4][8], const float rat[4]) {
  float prod = 1.f;
#pragma unroll
  for (int j = 0; j < 4; j++) {
    float pr[8];
    oct8(rat[j], pr);
    prod *= dot8(wup_p[j], pr);
  }
  return prod;
}

// level-7 node with its 4 leaf children folded in
static __device__ __forceinline__ float leaf7(float u7, float e0, float e1, float e2,
                                              float e3, float em, float* acc) {
  float n0 = bfly8(u7 * e0), n1 = bfly8(u7 * e1);
  float n2 = bfly8(u7 * e2), n3 = bfly8(u7 * e3);
  float p01 = n0 * n1, p23 = n2 * n3;
  float prod = (e0 * e1 * rcpf(p01)) * (e2 * e3 * rcpf(p23));
  *acc += __logf(p01) + __logf(p23);
  float nu7 = bfly8(u7 * em * prod);
  *acc += __logf(nu7);
  return em * prod * rcpf(nu7);
}

// shared phase-0 table build (per block): A/Pi/B softmaxes into LDS (emt stride 36)
static __device__ __forceinline__ void build_tables(const float* __restrict__ A,
                                                    const float* __restrict__ Bm,
                                                    const float* __restrict__ Pi,
                                                    float* wtd_l, float* emt_l,
                                                    float* pit_l, float* llb, int t) {
  if (t < 128) {  // A softmax over child state; thread owns column (d,j,gg)
    int d = t >> 4, j = (t >> 2) & 3, gg = t & 3;
    float v[8], sum = 0.f;
#pragma unroll
    for (int ss = 0; ss < 8; ss++) { v[ss] = __expf(A[((ss * 8 + d) * 4 + j) * 4 + gg]); sum += v[ss]; }
    float inv = rcpf(sum);
#pragma unroll
    for (int ss = 0; ss < 8; ss++) wtd_l[(j * 8 + d) * 32 + gg * 8 + ss] = v[ss] * inv;
  }
  if (t < 4) {  // Pi softmax
    float v[8], sum = 0.f;
#pragma unroll
    for (int c = 0; c < 8; c++) { v[c] = __expf(Pi[c * 4 + t]); sum += v[c]; }
    float inv = rcpf(sum);
#pragma unroll
    for (int c = 0; c < 8; c++) pit_l[t * 8 + c] = v[c] * inv;
    llb[t] = 0.f;
  }
  {  // emission softmax over m: 32 rows x 8 octet-partitions
    int row = t >> 3, part = t & 7, c = row >> 2, gg = row & 3;
    int m0 = part < 4 ? part * 13 : 52 + (part - 4) * 12;
    int mn = part < 4 ? 13 : 12;
    float sum = 0.f;
    for (int m = m0; m < m0 + mn; m++) sum += __expf(Bm[(c * 100 + m) * 4 + gg]);
    sum = bfly8(sum);
    float inv = rcpf(sum);
    for (int m = m0; m < m0 + mn; m++)
      emt_l[m * 36 + gg * 8 + c] = __expf(Bm[(c * 100 + m) * 4 + gg]) * inv;
  }
}

// ---------------- kernel 1: levels 8..4 (rolled q6, unrolled q7) ----------------
// 1024 blocks x 256. Each 32-lane group walks ONE level-5 subtree.
__global__ __launch_bounds__(256) void k_phase1(const int* __restrict__ x,
                                                const float* __restrict__ A,
                                                const float* __restrict__ Bm,
                                                const float* __restrict__ Pi,
                                                float* __restrict__ RAT4,
                                                float* __restrict__ blocksum) {
  __shared__ __align__(16) float wtd_l[1024];
  __shared__ __align__(16) float wtdT[1280];  // 128 rows x stride 10 (down)
  __shared__ __align__(16) float wupT[1280];  // 128 rows x stride 10 (up)
  __shared__ __align__(16) float emt_l[3600]; // 100 rows x stride 36
  __shared__ __align__(16) float pit_l[32];
  __shared__ __align__(16) int   xle[680];    // [0:512) leaf, [512:640) l7, [640:672) l6, [672:680) l5
  __shared__ __align__(16) float xb[320];     // rat5 rows [0..255] + pri4 rows [256..319]
  __shared__ float llb[4];

  int t = threadIdx.x;
  int r = t & 31, g = r >> 3, s = r & 7, grp = t >> 5;
  int h = s >> 2, gb = g * 8;
  int sg = s * 4 + g;                  // stride-10 table row index within a j-bank
  int b = blockIdx.x;

  build_tables(A, Bm, Pi, wtd_l, emt_l, pit_l, llb, t);
  // stage this block's observation indices (coalesced; no global loads in-loop)
  xle[t] = x[OFFS8 + b * 512 + t];
  xle[256 + t] = x[OFFS8 + b * 512 + 256 + t];
  if (t < 128) xle[512 + t] = x[OFFS7 + b * 128 + t];
  if (t < 32) xle[640 + t] = x[OFFS6 + b * 32 + t];
  if (t < 8) xle[672 + t] = x[OFFS5 + b * 8 + t];
  __syncthreads();
  if (t < 128) {  // build stride-10 transposed tables (row t = j*32 + ss*4+gg)
    int j = t >> 5, ss = (t >> 2) & 7, gg = t & 3;
#pragma unroll
    for (int d = 0; d < 8; d++) {
      wtdT[t * 10 + d] = wtd_l[(j * 8 + d) * 32 + gg * 8 + ss];   // over parent d
      wupT[t * 10 + d] = wtd_l[(j * 8 + ss) * 32 + gg * 8 + d];   // over child c
    }
  }
  // register weight sets (static-j uses only):
  //  wtd_p[j][i] = P(child=s | parent=perm(i), j, g)   (u7 dots)
  //  wup_p[j][i] = P(child=perm(i) | parent=s, j, g)   (E dots, q7 folds)
  float wtd_p[4][8], wup_p[4][8];
#pragma unroll
  for (int j = 0; j < 4; j++) {
    const float* wb = &wtd_l[j * 256 + r];
#pragma unroll
    for (int k = 0; k < 4; k++) {
      wtd_p[j][k]     = wb[(4 * h + k) * 32];
      wtd_p[j][4 + k] = wb[(7 - 4 * h - k) * 32];
    }
    ld8p(&wtd_l[(j * 8 + s) * 32 + gb], wup_p[j], h);
  }
  __syncthreads();  // wtdT/wupT ready

  float acc = 0.f;
  int n5 = b * 8 + grp;

  // top-down prior (rolled, runtime child positions)
  float v5 = pit_l[r], pri4 = 0.f;
#pragma unroll 1
  for (int k = 1; k <= 5; k++) {
    v5 = step_downT(wtdT, v5, (n5 >> (2 * (5 - k))) & 3, sg, h);
    if (k == 4) pri4 = v5;
  }
  float pv5[8];
  oct8(v5, pv5);

  float prod5 = 1.f;
#pragma unroll 1
  for (int q6 = 0; q6 < 4; q6++) {
    float u6 = dot8pT(pv5, &wtdT[(q6 * 32 + sg) * 10], h);
    float pv6[8];
    oct8(u6, pv6);
    float prod6 = 1.f;
#pragma unroll
    for (int q7 = 0; q7 < 4; q7++) {  // UNROLLED: static register weights
      int4 xl = ((const int4*)xle)[grp * 16 + q6 * 4 + q7];  // group-uniform broadcast
      const int* xa = (const int*)&xl;
      // leaf operator on the fly: E = sum_c P(c|s,j,g) em(m|c,g)  (static j)
      float E[4];
#pragma unroll
      for (int j = 0; j < 4; j++) E[j] = dot8p(wup_p[j], &emt_l[xa[j] * 36 + gb], h);
      float u7 = dot8(wtd_p[q7], pv6);
      float em7 = emt_l[xle[512 + grp * 16 + q6 * 4 + q7] * 36 + r];
      float rat7 = leaf7(u7, E[0], E[1], E[2], E[3], em7, &acc);
      // fold child q7 into the level-6 product (static q7 -> register wup_p)
      float pr[8];
      oct8(rat7, pr);
      prod6 *= dot8(wup_p[q7], pr);
    }
    float em6 = emt_l[xle[640 + grp * 4 + q6] * 36 + r];
    float nu6 = bfly8(u6 * em6 * prod6);
    acc += __logf(nu6);
    float rat6 = em6 * prod6 * rcpf(nu6);
    float pr6[8];
    oct8(rat6, pr6);
    prod5 *= dot8pT(pr6, &wupT[(q6 * 32 + sg) * 10], h);  // runtime q6 -> LDS
  }
  float em5 = emt_l[xle[672 + grp] * 36 + r];
  float nu5 = bfly8(v5 * em5 * prod5);
  acc += __logf(nu5);
  xb[grp * 32 + r] = em5 * prod5 * rcpf(nu5);
  if ((grp & 3) == 0) xb[256 + (grp >> 2) * 32 + r] = pri4;
  __syncthreads();

  // level-4: 2 nodes per block, groups 0-1; plain store (stream-order barrier)
  if (grp < 2) {
    int n4 = b * 2 + grp;
    float prod = 1.f;
#pragma unroll
    for (int j = 0; j < 4; j++) prod *= dot8p(wup_p[j], &xb[(grp * 4 + j) * 32 + gb], h);
    float em = emt_l[x[OFFS4 + n4] * 36 + r];
    float pr4 = xb[256 + grp * 32 + r];
    float nu = bfly8(pr4 * em * prod);
    acc += __logf(nu);
    RAT4[n4 * 32 + r] = em * prod * rcpf(nu);
  }

  if (s == 0) atomicAdd(&llb[g], acc);
  __syncthreads();
  if (t < 4) blocksum[b * 4 + t] = llb[t];
}

// ---------------- kernel 2: levels 3..0 + final reduce ----------------
// 8 blocks x 256, one per tree. Stream order guarantees RAT4/blocksum ready.
__global__ __launch_bounds__(256) void k_phase2(const int* __restrict__ x,
                                                const float* __restrict__ A,
                                                const float* __restrict__ Bm,
                                                const float* __restrict__ Pi,
                                                const float* __restrict__ RAT4,
                                                const float* __restrict__ blocksum,
                                                float* __restrict__ out) {
  __shared__ __align__(16) float wtd_l[1024];
  __shared__ __align__(16) float emt_l[3600];
  __shared__ __align__(16) float pit_l[32];
  __shared__ __align__(16) float stg[8192];  // full 32 KB RAT4 tree slice / reduce buf
  __shared__ __align__(16) float xb[640];    // rat2 rows [0..511], rat1 rows [512..639]
  __shared__ float llb[4];

  int t = threadIdx.x;
  int r = t & 31, g = r >> 3, s = r & 7, grp = t >> 5;
  int h = s >> 2, gb = g * 8;
  int tree = blockIdx.x;

  build_tables(A, Bm, Pi, wtd_l, emt_l, pit_l, llb, t);
  // stage the tree's RAT4 slice: 8192 floats, coalesced float4
  {
    const float4* src = (const float4*)(RAT4 + tree * 8192);
    float4* dst = (float4*)stg;
#pragma unroll
    for (int i = 0; i < 8; i++) dst[i * 256 + t] = src[i * 256 + t];
  }
  __syncthreads();

  float wtd_p[4][8], wup_p[4][8];
#pragma unroll
  for (int j = 0; j < 4; j++) {
    const float* wb = &wtd_l[j * 256 + r];
#pragma unroll
    for (int k = 0; k < 4; k++) {
      wtd_p[j][k]     = wb[(4 * h + k) * 32];
      wtd_p[j][4 + k] = wb[(7 - 4 * h - k) * 32];
    }
    ld8p(&wtd_l[(j * 8 + s) * 32 + gb], wup_p[j], h);
  }

  float acc2 = 0.f;
  {  // two level-2 subtrees per group, interleaved (A: l2=grp, B: l2=8+grp)
    int n2A = tree * 16 + grp, n2B = n2A + 8;
    int4 x3A = *(const int4*)(x + OFFS3 + n2A * 4);
    int4 x3B = *(const int4*)(x + OFFS3 + n2B * 4);
    int x2A = x[OFFS2 + n2A], x2B = x[OFFS2 + n2B];
    const int* xa = (const int*)&x3A;
    const int* xbv = (const int*)&x3B;
    float v2A = pit_l[r], v2B = v2A;
    v2A = step_down(wtd_l, v2A, (n2A >> 2) & 3, r, h);
    v2B = step_down(wtd_l, v2B, (n2B >> 2) & 3, r, h);
    v2A = step_down(wtd_l, v2A, n2A & 3, r, h);
    v2B = step_down(wtd_l, v2B, n2B & 3, r, h);
    float pv2A[8], pv2B[8];
    oct8(v2A, pv2A); oct8(v2B, pv2B);
    float rat3A[4], rat3B[4];
#pragma unroll
    for (int j3 = 0; j3 < 4; j3++) {
      int i3A = grp * 4 + j3, i3B = (8 + grp) * 4 + j3;  // local L3 index 0..63
      float p3A = dot8(wtd_p[j3], pv2A);
      float p3B = dot8(wtd_p[j3], pv2B);
      float prodA = 1.f, prodB = 1.f;
#pragma unroll
      for (int j = 0; j < 4; j++) {
        prodA *= dot8p(wup_p[j], &stg[(i3A * 4 + j) * 32 + gb], h);
        prodB *= dot8p(wup_p[j], &stg[(i3B * 4 + j) * 32 + gb], h);
      }
      float emA = emt_l[xa[j3] * 36 + r], emB = emt_l[xbv[j3] * 36 + r];
      float nuA = bfly8(p3A * emA * prodA), nuB = bfly8(p3B * emB * prodB);
      acc2 += __logf(nuA) + __logf(nuB);
      rat3A[j3] = emA * prodA * rcpf(nuA);
      rat3B[j3] = emB * prodB * rcpf(nuB);
    }
    float prodA = upprod(wup_p, rat3A);
    float prodB = upprod(wup_p, rat3B);
    float emA = emt_l[x2A * 36 + r], emB = emt_l[x2B * 36 + r];
    float nuA = bfly8(v2A * emA * prodA), nuB = bfly8(v2B * emB * prodB);
    acc2 += __logf(nuA) + __logf(nuB);
    xb[grp * 32 + r] = emA * prodA * rcpf(nuA);        // rat2 row l2=grp
    xb[(8 + grp) * 32 + r] = emB * prodB * rcpf(nuB);  // rat2 row l2=8+grp
  }
  __syncthreads();
  if (grp < 4) {  // level 1
    int n1g = tree * 4 + grp;
    float v1 = step_down(wtd_l, pit_l[r], grp, r, h);
    float prod = 1.f;
#pragma unroll
    for (int j = 0; j < 4; j++) prod *= dot8p(wup_p[j], &xb[(grp * 4 + j) * 32 + gb], h);
    float em = emt_l[x[OFFS1 + n1g] * 36 + r];
    float nu = bfly8(v1 * em * prod);
    acc2 += __logf(nu);
    xb[512 + grp * 32 + r] = em * prod * rcpf(nu);  // rat1 row
  }
  __syncthreads();
  if (grp == 0) {  // root
    float pr = pit_l[r];
    float prod = 1.f;
#pragma unroll
    for (int j = 0; j < 4; j++) prod *= dot8p(wup_p[j], &xb[512 + j * 32 + gb], h);
    float em = emt_l[x[tree] * 36 + r];
    float nu = bfly8(pr * em * prod);
    acc2 += __logf(nu);
  }
  __syncthreads();
  if (s == 0) atomicAdd(&llb[g], acc2);
  // reduce this tree's 128 phase-1 blocks x 4 partial sums (512 values, 2/thread)
  float v = blocksum[tree * 512 + t] + blocksum[tree * 512 + 256 + t];
  __syncthreads();
  stg[t] = v;
  __syncthreads();
#pragma unroll
  for (int off = 128; off >= 4; off >>= 1) {
    if (t < off) stg[t] += stg[t + off];
    __syncthreads();
  }
  if (t < 4) out[tree * 4 + t] = stg[t] + llb[t];
}

extern "C" void kernel_launch(void* const* d_in, const int* in_sizes, int n_in,
                              void* d_out, int out_size, void* d_ws, size_t ws_size,
                              hipStream_t stream) {
  const int* x = (const int*)d_in[0];
  const float* A = (const float*)d_in[1];
  const float* Bm = (const float*)d_in[2];
  const float* Pi = (const float*)d_in[3];
  float* ws = (float*)d_ws;
  float* blocksum = ws + 256;        // 1024 blocks x 4
  float* RAT4 = ws + 256 + 4096;     // 2048*32
  float* out = (float*)d_out;

  k_phase1<<<1024, 256, 0, stream>>>(x, A, Bm, Pi, RAT4, blocksum);
  k_phase2<<<8, 256, 0, stream>>>(x, A, Bm, Pi, RAT4, blocksum, out);
}

// Round 10
// 94.519 us; speedup vs baseline: 1.0839x; 1.0839x over previous
//
#include <hip/hip_runtime.h>

// HTMM: B_TREES=8, ARITY=4, DEPTH=8, C=8, M=100, NGEN=4
constexpr int OFFS1 = 8, OFFS2 = 40, OFFS3 = 168, OFFS4 = 680;
constexpr int OFFS5 = 2728, OFFS6 = 10920, OFFS7 = 43688, OFFS8 = 174760;

// lane mapping within a 32-lane group: r = g*8+s (g = gen, s = state), h = s>>2
// wtd_l[(j*8+d)*32 + g*8+s] = P(child=s | parent=d, pos j, gen g)
// emt_l[m*32 + g*8+c] = P(obs m | state c, gen g)  (scalar reads only in k1)
// etab_l[(m*4+j)*32 + g*8+d] = sum_c P(c|d,j,g)*em(m|c,g)  — leaf upward
//   operator table (r0's trick, restored): E-read = 1 scalar ds_read at bank
//   r mod 32 (2 lanes/bank = free) instead of 2x b128 + 8 FMA + addressing.
// pit_l[g*8+c] = root prior
//
// r10 model (fits r0-r9): dur = waves x stream_len x 2cyc / (1024 SIMD x eff).
// Waves fixed at 4096 total; levers are stream length and efficiency. etab
// shortens the stream ~25% (the E re-derivation was a third of it); the
// sequential round loop keeps single-walk code (~20 KB, I-cache resident) and
// single-subtree live state (VGPR <= 128 via launch_bounds(256,2), r5-proven).
// Two-kernel split (r6, best measured) keeps the tree tail off the hot path.

template <int CTRL>
static __device__ __forceinline__ float dppmov(float v) {
  return __int_as_float(__builtin_amdgcn_update_dpp(0, __float_as_int(v), CTRL, 0xF, 0xF, true));
}

// octet all-reduce sum, result broadcast to all 8 lanes. Pure DPP (no LDS).
static __device__ __forceinline__ float bfly8(float v) {
  v += dppmov<0xB1>(v);   // quad_perm [1,0,3,2]  (xor 1)
  v += dppmov<0x4E>(v);   // quad_perm [2,3,0,1]  (xor 2)
  v += dppmov<0x141>(v);  // row_half_mirror      (cross-quad within octet)
  return v;
}

// gather own-octet values: pv[k] = v[oct | 4h+k], pv[4+k] = v[oct | 7-4h-k]
static __device__ __forceinline__ void oct8(float v, float pv[8]) {
  float m = dppmov<0x141>(v);  // half-mirror: m[l] = v[oct | 7-(l&7)]
  pv[0] = dppmov<0x00>(v); pv[1] = dppmov<0x55>(v);
  pv[2] = dppmov<0xAA>(v); pv[3] = dppmov<0xFF>(v);
  pv[4] = dppmov<0x00>(m); pv[5] = dppmov<0x55>(m);
  pv[6] = dppmov<0xAA>(m); pv[7] = dppmov<0xFF>(m);
}

static __device__ __forceinline__ float dot8(const float w[8], const float v[8]) {
  return w[0]*v[0] + w[1]*v[1] + w[2]*v[2] + w[3]*v[3] +
         w[4]*v[4] + w[5]*v[5] + w[6]*v[6] + w[7]*v[7];
}

static __device__ __forceinline__ void ld8(const float* p, float pv[8]) {
  const float4* q = (const float4*)p;
  float4 a = q[0], b = q[1];
  pv[0] = a.x; pv[1] = a.y; pv[2] = a.z; pv[3] = a.w;
  pv[4] = b.x; pv[5] = b.y; pv[6] = b.z; pv[7] = b.w;
}

// load 8 consecutive floats permuted to the oct8 register order
static __device__ __forceinline__ void ld8p(const float* p, float wp[8], int h) {
  const float4* q = (const float4*)p;
  float4 a = q[h], b = q[1 - h];
  wp[0] = a.x; wp[1] = a.y; wp[2] = a.z; wp[3] = a.w;
  wp[4] = b.w; wp[5] = b.z; wp[6] = b.y; wp[7] = b.x;
}

// dot of a permuted register 8-vector with a natural-order 8-vector in LDS (2x b128)
static __device__ __forceinline__ float dot8p(const float wp[8], const float* p, int h) {
  const float4* q = (const float4*)p;
  float4 a = q[h], b = q[1 - h];
  return wp[0]*a.x + wp[1]*a.y + wp[2]*a.z + wp[3]*a.w +
         wp[4]*b.w + wp[5]*b.z + wp[6]*b.y + wp[7]*b.x;
}

static __device__ __forceinline__ float dot8r(const float w[8], const float* p) {
  const float4* q = (const float4*)p;
  float4 a = q[0], b = q[1];
  return w[0]*a.x + w[1]*a.y + w[2]*a.z + w[3]*a.w +
         w[4]*b.x + w[5]*b.y + w[6]*b.z + w[7]*b.w;
}

static __device__ __forceinline__ float rcpf(float x) { return __builtin_amdgcn_rcpf(x); }

// one top-down prior step with runtime child-position j (scalar weight gather)
static __device__ __forceinline__ float step_down(const float* wtd_l, float v, int j,
                                                  int r, int h) {
  const float* wb = &wtd_l[j * 256 + r];
  float w[8];
#pragma unroll
  for (int k = 0; k < 4; k++) {
    w[k]     = wb[(4 * h + k) * 32];
    w[4 + k] = wb[(7 - 4 * h - k) * 32];
  }
  float pv[8];
  oct8(v, pv);
  return dot8(w, pv);
}

// upward product over 4 children whose rat values live in registers (octet DPP gather)
static __device__ __forceinline__ float upprod(const float wup_p[4][8], const float rat[4]) {
  float prod = 1.f;
#pragma unroll
  for (int j = 0; j < 4; j++) {
    float pr[8];
    oct8(rat[j], pr);
    prod *= dot8(wup_p[j], pr);
  }
  return prod;
}

// level-7 node with its 4 leaf children folded in (E from etab)
static __device__ __forceinline__ float leaf7(float u7, float e0, float e1, float e2,
                                              float e3, float em, float* acc) {
  float n0 = bfly8(u7 * e0), n1 = bfly8(u7 * e1);
  float n2 = bfly8(u7 * e2), n3 = bfly8(u7 * e3);
  float p01 = n0 * n1, p23 = n2 * n3;
  float prod = (e0 * e1 * rcpf(p01)) * (e2 * e3 * rcpf(p23));
  *acc += __logf(p01) + __logf(p23);
  float nu7 = bfly8(u7 * em * prod);
  *acc += __logf(nu7);
  return em * prod * rcpf(nu7);
}

// shared phase-0 table build (per block): A/Pi/B softmaxes into LDS (emt stride 32)
static __device__ __forceinline__ void build_tables(const float* __restrict__ A,
                                                    const float* __restrict__ Bm,
                                                    const float* __restrict__ Pi,
                                                    float* wtd_l, float* emt_l,
                                                    float* pit_l, float* llb, int t) {
  if (t < 128) {  // A softmax over child state; thread owns column (d,j,gg)
    int d = t >> 4, j = (t >> 2) & 3, gg = t & 3;
    float v[8], sum = 0.f;
#pragma unroll
    for (int ss = 0; ss < 8; ss++) { v[ss] = __expf(A[((ss * 8 + d) * 4 + j) * 4 + gg]); sum += v[ss]; }
    float inv = rcpf(sum);
#pragma unroll
    for (int ss = 0; ss < 8; ss++) wtd_l[(j * 8 + d) * 32 + gg * 8 + ss] = v[ss] * inv;
  }
  if (t < 4) {  // Pi softmax
    float v[8], sum = 0.f;
#pragma unroll
    for (int c = 0; c < 8; c++) { v[c] = __expf(Pi[c * 4 + t]); sum += v[c]; }
    float inv = rcpf(sum);
#pragma unroll
    for (int c = 0; c < 8; c++) pit_l[t * 8 + c] = v[c] * inv;
    llb[t] = 0.f;
  }
  {  // emission softmax over m: 32 rows x 8 octet-partitions
    int row = t >> 3, part = t & 7, c = row >> 2, gg = row & 3;
    int m0 = part < 4 ? part * 13 : 52 + (part - 4) * 12;
    int mn = part < 4 ? 13 : 12;
    float sum = 0.f;
    for (int m = m0; m < m0 + mn; m++) sum += __expf(Bm[(c * 100 + m) * 4 + gg]);
    sum = bfly8(sum);
    float inv = rcpf(sum);
    for (int m = m0; m < m0 + mn; m++)
      emt_l[m * 32 + gg * 8 + c] = __expf(Bm[(c * 100 + m) * 4 + gg]) * inv;
  }
}

// ---------------- kernel 1: levels 8..4 ----------------
// 512 blocks x 256. Each 32-lane group does 2 L5 subtrees SEQUENTIALLY
// (rolled round loop -> single-walk code, single-subtree register state);
// block covers 16 L5 nodes = 4 L4 nodes. Writes RAT4 + blocksum.
__global__ __launch_bounds__(256, 2) void k_phase1(const int* __restrict__ x,
                                                   const float* __restrict__ A,
                                                   const float* __restrict__ Bm,
                                                   const float* __restrict__ Pi,
                                                   float* __restrict__ RAT4,
                                                   float* __restrict__ blocksum) {
  __shared__ __align__(16) float wtd_l[1024];
  __shared__ __align__(16) float emt_l[3200];
  __shared__ __align__(16) float etab_l[12800];
  __shared__ __align__(16) float pit_l[32];
  __shared__ __align__(16) float rat5buf[16][32];
  __shared__ __align__(16) float pri4buf[4][32];
  __shared__ float llb[4];

  int t = threadIdx.x;
  int r = t & 31, g = r >> 3, s = r & 7, grp = t >> 5;
  int h = s >> 2, gb = g * 8;
  int b = blockIdx.x;

  build_tables(A, Bm, Pi, wtd_l, emt_l, pit_l, llb, t);
  __syncthreads();
  {  // etab: 12800 entries; combo (j,d,gg) = t&127, m-half = t>>7  (r0's build)
    int c7 = t & 127, half = t >> 7;
    int j = c7 >> 5, d = (c7 >> 2) & 7, gg = c7 & 3;
    float w[8];
    ld8(&wtd_l[(j * 8 + d) * 32 + gg * 8], w);
    for (int m = half * 50; m < half * 50 + 50; m++)
      etab_l[(m * 4 + j) * 32 + gg * 8 + d] = dot8r(w, &emt_l[m * 32 + gg * 8]);
  }
  // register weight sets (wtd_l stable from here):
  //  wtd_p[j][i] = P(child=s | parent=perm(i), j, g)   (parent-sum dots)
  //  wup_p[j][i] = P(child=perm(i) | parent=s, j, g)   (child-sum dots)
  float wtd_p[4][8], wup_p[4][8];
#pragma unroll
  for (int j = 0; j < 4; j++) {
    const float* wb = &wtd_l[j * 256 + r];
#pragma unroll
    for (int k = 0; k < 4; k++) {
      wtd_p[j][k]     = wb[(4 * h + k) * 32];
      wtd_p[j][4 + k] = wb[(7 - 4 * h - k) * 32];
    }
    ld8p(&wtd_l[(j * 8 + s) * 32 + gb], wup_p[j], h);
  }
  __syncthreads();  // etab ready

  float acc = 0.f;
#pragma unroll 1
  for (int round = 0; round < 2; round++) {
    int n5 = b * 16 + round * 8 + grp;
    const int4* x8v = (const int4*)(x + OFFS8 + n5 * 64);
    const int4* x7p = (const int4*)(x + OFFS7 + n5 * 16);
    int4 x6v = *(const int4*)(x + OFFS6 + n5 * 4);
    int x5s = x[OFFS5 + n5];
    const int* x6a = (const int*)&x6v;

    // top-down prior to this L5 node (5 steps, runtime child positions)
    float v5 = pit_l[r], pri4 = 0.f;
#pragma unroll
    for (int k = 1; k <= 5; k++) {
      v5 = step_down(wtd_l, v5, (n5 >> (2 * (5 - k))) & 3, r, h);
      if (k == 4) pri4 = v5;
    }
    float pv5[8];
    oct8(v5, pv5);

    float rat6[4];
#pragma unroll
    for (int q6 = 0; q6 < 4; q6++) {
      float u6 = dot8(wtd_p[q6], pv5);
      float pv6[8];
      oct8(u6, pv6);
      int4 x7q = x7p[q6];
      const int* x7a = (const int*)&x7q;

      float rat7[4];
#pragma unroll
      for (int q7 = 0; q7 < 4; q7++) {
        int4 xl = x8v[q6 * 4 + q7];
        const int* xa = (const int*)&xl;
        // leaf operator from etab: one scalar read per leaf position
        float E[4];
#pragma unroll
        for (int j = 0; j < 4; j++) E[j] = etab_l[(xa[j] * 4 + j) * 32 + r];
        float u7 = dot8(wtd_p[q7], pv6);
        rat7[q7] = leaf7(u7, E[0], E[1], E[2], E[3], emt_l[x7a[q7] * 32 + r], &acc);
      }
      float prod6 = upprod(wup_p, rat7);
      float em6 = emt_l[x6a[q6] * 32 + r];
      float nu6 = bfly8(u6 * em6 * prod6);
      acc += __logf(nu6);
      rat6[q6] = em6 * prod6 * rcpf(nu6);
    }
    // level-5 upward -> rat5 row (cross-group consumers, so LDS)
    float prod5 = upprod(wup_p, rat6);
    float em5 = emt_l[x5s * 32 + r];
    float nu5 = bfly8(v5 * em5 * prod5);
    acc += __logf(nu5);
    rat5buf[round * 8 + grp][r] = em5 * prod5 * rcpf(nu5);
    if ((grp & 3) == 0) pri4buf[round * 2 + (grp >> 2)][r] = pri4;
  }
  __syncthreads();

  // level-4: 4 nodes per block, groups 0-3; plain store (stream-order barrier)
  if (grp < 4) {
    int n4 = b * 4 + grp;
    float prod = 1.f;
#pragma unroll
    for (int j = 0; j < 4; j++) prod *= dot8p(wup_p[j], &rat5buf[grp * 4 + j][gb], h);
    float em = emt_l[x[OFFS4 + n4] * 32 + r];
    float pr4 = pri4buf[grp][r];
    float nu = bfly8(pr4 * em * prod);
    acc += __logf(nu);
    RAT4[n4 * 32 + r] = em * prod * rcpf(nu);
  }

  if (s == 0) atomicAdd(&llb[g], acc);
  __syncthreads();
  if (t < 4) blocksum[b * 4 + t] = llb[t];
}

// ---------------- kernel 2: levels 3..0 + final reduce ----------------
// 8 blocks x 256, one per tree. Stream order guarantees RAT4/blocksum ready.
__global__ __launch_bounds__(256) void k_phase2(const int* __restrict__ x,
                                                const float* __restrict__ A,
                                                const float* __restrict__ Bm,
                                                const float* __restrict__ Pi,
                                                const float* __restrict__ RAT4,
                                                const float* __restrict__ blocksum,
                                                float* __restrict__ out) {
  __shared__ __align__(16) float wtd_l[1024];
  __shared__ __align__(16) float emt_l[3200];
  __shared__ __align__(16) float pit_l[32];
  __shared__ __align__(16) float stg[8192];  // full 32 KB RAT4 tree slice / reduce buf
  __shared__ __align__(16) float xb[640];    // rat2 rows [0..511], rat1 rows [512..639]
  __shared__ float llb[4];

  int t = threadIdx.x;
  int r = t & 31, g = r >> 3, s = r & 7, grp = t >> 5;
  int h = s >> 2, gb = g * 8;
  int tree = blockIdx.x;

  build_tables(A, Bm, Pi, wtd_l, emt_l, pit_l, llb, t);
  // stage the tree's RAT4 slice: 8192 floats, coalesced float4
  {
    const float4* src = (const float4*)(RAT4 + tree * 8192);
    float4* dst = (float4*)stg;
#pragma unroll
    for (int i = 0; i < 8; i++) dst[i * 256 + t] = src[i * 256 + t];
  }
  __syncthreads();

  float wtd_p[4][8], wup_p[4][8];
#pragma unroll
  for (int j = 0; j < 4; j++) {
    const float* wb = &wtd_l[j * 256 + r];
#pragma unroll
    for (int k = 0; k < 4; k++) {
      wtd_p[j][k]     = wb[(4 * h + k) * 32];
      wtd_p[j][4 + k] = wb[(7 - 4 * h - k) * 32];
    }
    ld8p(&wtd_l[(j * 8 + s) * 32 + gb], wup_p[j], h);
  }

  float acc2 = 0.f;
  {  // two level-2 subtrees per group, interleaved (A: l2=grp, B: l2=8+grp)
    int n2A = tree * 16 + grp, n2B = n2A + 8;
    int4 x3A = *(const int4*)(x + OFFS3 + n2A * 4);
    int4 x3B = *(const int4*)(x + OFFS3 + n2B * 4);
    int x2A = x[OFFS2 + n2A], x2B = x[OFFS2 + n2B];
    const int* xa = (const int*)&x3A;
    const int* xbv = (const int*)&x3B;
    float v2A = pit_l[r], v2B = v2A;
    v2A = step_down(wtd_l, v2A, (n2A >> 2) & 3, r, h);
    v2B = step_down(wtd_l, v2B, (n2B >> 2) & 3, r, h);
    v2A = step_down(wtd_l, v2A, n2A & 3, r, h);
    v2B = step_down(wtd_l, v2B, n2B & 3, r, h);
    float pv2A[8], pv2B[8];
    oct8(v2A, pv2A); oct8(v2B, pv2B);
    float rat3A[4], rat3B[4];
#pragma unroll
    for (int j3 = 0; j3 < 4; j3++) {
      int i3A = grp * 4 + j3, i3B = (8 + grp) * 4 + j3;  // local L3 index 0..63
      float p3A = dot8(wtd_p[j3], pv2A);
      float p3B = dot8(wtd_p[j3], pv2B);
      float prodA = 1.f, prodB = 1.f;
#pragma unroll
      for (int j = 0; j < 4; j++) {
        prodA *= dot8p(wup_p[j], &stg[(i3A * 4 + j) * 32 + gb], h);
        prodB *= dot8p(wup_p[j], &stg[(i3B * 4 + j) * 32 + gb], h);
      }
      float emA = emt_l[xa[j3] * 32 + r], emB = emt_l[xbv[j3] * 32 + r];
      float nuA = bfly8(p3A * emA * prodA), nuB = bfly8(p3B * emB * prodB);
      acc2 += __logf(nuA) + __logf(nuB);
      rat3A[j3] = emA * prodA * rcpf(nuA);
      rat3B[j3] = emB * prodB * rcpf(nuB);
    }
    float prodA = upprod(wup_p, rat3A);
    float prodB = upprod(wup_p, rat3B);
    float emA = emt_l[x2A * 32 + r], emB = emt_l[x2B * 32 + r];
    float nuA = bfly8(v2A * emA * prodA), nuB = bfly8(v2B * emB * prodB);
    acc2 += __logf(nuA) + __logf(nuB);
    xb[grp * 32 + r] = emA * prodA * rcpf(nuA);        // rat2 row l2=grp
    xb[(8 + grp) * 32 + r] = emB * prodB * rcpf(nuB);  // rat2 row l2=8+grp
  }
  __syncthreads();
  if (grp < 4) {  // level 1
    int n1g = tree * 4 + grp;
    float v1 = step_down(wtd_l, pit_l[r], grp, r, h);
    float prod = 1.f;
#pragma unroll
    for (int j = 0; j < 4; j++) prod *= dot8p(wup_p[j], &xb[(grp * 4 + j) * 32 + gb], h);
    float em = emt_l[x[OFFS1 + n1g] * 32 + r];
    float nu = bfly8(v1 * em * prod);
    acc2 += __logf(nu);
    xb[512 + grp * 32 + r] = em * prod * rcpf(nu);  // rat1 row
  }
  __syncthreads();
  if (grp == 0) {  // root
    float pr = pit_l[r];
    float prod = 1.f;
#pragma unroll
    for (int j = 0; j < 4; j++) prod *= dot8p(wup_p[j], &xb[512 + j * 32 + gb], h);
    float em = emt_l[x[tree] * 32 + r];
    float nu = bfly8(pr * em * prod);
    acc2 += __logf(nu);
  }
  __syncthreads();
  if (s == 0) atomicAdd(&llb[g], acc2);
  // reduce this tree's 64 phase-1 blocks x 4 partial sums (256 values)
  float v = blocksum[tree * 256 + t];
  __syncthreads();
  stg[t] = v;
  __syncthreads();
#pragma unroll
  for (int off = 128; off >= 4; off >>= 1) {
    if (t < off) stg[t] += stg[t + off];
    __syncthreads();
  }
  if (t < 4) out[tree * 4 + t] = stg[t] + llb[t];
}

extern "C" void kernel_launch(void* const* d_in, const int* in_sizes, int n_in,
                              void* d_out, int out_size, void* d_ws, size_t ws_size,
                              hipStream_t stream) {
  const int* x = (const int*)d_in[0];
  const float* A = (const float*)d_in[1];
  const float* Bm = (const float*)d_in[2];
  const float* Pi = (const float*)d_in[3];
  float* ws = (float*)d_ws;
  float* blocksum = ws + 256;        // 512 blocks x 4
  float* RAT4 = ws + 256 + 2048;     // 2048*32
  float* out = (float*)d_out;

  k_phase1<<<512, 256, 0, stream>>>(x, A, Bm, Pi, RAT4, blocksum);
  k_phase2<<<8, 256, 0, stream>>>(x, A, Bm, Pi, RAT4, blocksum, out);
}